// Round 9
// baseline (305.687 us; speedup 1.0000x reference)
//
#include <hip/hip_runtime.h>
#include <math.h>

#define NN 500000
#define CH 128
#define NG 1024
#define GRID 256
#define TILES ((NN + 127) >> 7)   // 3907 tiles of 128 rows

typedef __attribute__((ext_vector_type(8))) short short8v;
typedef __attribute__((ext_vector_type(4))) float f32x4;

__device__ __forceinline__ void bf16_split(float f, unsigned short& h, unsigned short& l){
  const unsigned u = __float_as_uint(f);
  h = (unsigned short)(u >> 16);
  const float hif = __uint_as_float(u & 0xffff0000u);
  const float lof = f - hif;
  l = (unsigned short)(__float_as_uint(lof) >> 16);
}

__device__ __forceinline__ void gld_lds16(const void* g, void* l){
  __builtin_amdgcn_global_load_lds(
      (__attribute__((address_space(1))) void*)g,
      (__attribute__((address_space(3))) void*)l, 16, 0, 0);
}
__device__ __forceinline__ void gld_lds4(const void* g, void* l){
  __builtin_amdgcn_global_load_lds(
      (__attribute__((address_space(1))) void*)g,
      (__attribute__((address_space(3))) void*)l, 4, 0, 0);
}

// Prep: (a) t<2048: transpose + bf16-hi/lo-split W1 into Wg, LINEAR layout:
// hi[n][k] at Wg + n*128 + k, lo at Wg + 16384 + n*128 + k (ushort units).
// (b) zero out[NG*CH] and den[NG].
__global__ __launch_bounds__(256) void prep_kernel(
    const float* __restrict__ W1, unsigned short* __restrict__ Wg,
    float* __restrict__ out, float* __restrict__ den){
  const int t = blockIdx.x * 256 + threadIdx.x;
  if (t < 2048){
    const int n  = t >> 4;          // out-channel 0..127
    const int k0 = (t & 15) << 3;   // 0,8,...,120
    unsigned short hv[8], lv[8];
    #pragma unroll
    for (int i = 0; i < 8; i++)
      bf16_split(W1[(size_t)(k0 + i) * CH + n], hv[i], lv[i]);
    *reinterpret_cast<short8v*>(Wg + n * 128 + k0) = *reinterpret_cast<short8v*>(hv);
    *reinterpret_cast<short8v*>(Wg + 16384 + n * 128 + k0) = *reinterpret_cast<short8v*>(lv);
  }
  const float4 z = make_float4(0.f, 0.f, 0.f, 0.f);
  float4* out4 = reinterpret_cast<float4*>(out);
  float4* den4 = reinterpret_cast<float4*>(den);
  const int nthr = gridDim.x * 256;
  for (int i = t; i < 32768 + 256; i += nthr){
    if (i < 32768) out4[i] = z;
    else den4[i - 32768] = z;
  }
}

// Fused single-pass: per 128-row tile: scores via 3-term bf16-split MFMA
// (W in REGISTERS), e=exp(s), pooling from the SAME LDS tile -> atomics.
// 8 waves (512 thr). LDS: 8 x 16KB K-slice slots (double tile) + handoff bufs.
// Pipeline: counted vmcnt(6) per phase; queue holds ONLY stage ops + (newest)
// a few atomics/batch-loads, so the wait retires exactly the consumed slice:
//   ops issued after slice(t,ks) = 2*(3-ks) [rest of t] + 2*ks [t+1 so far]
//   (+1 bsg for waves 0-1) = 6(+1) >= 6  ->  vmcnt(6) is always sufficient.
__global__ __launch_bounds__(512) void fused_kernel(
    const float* __restrict__ x, const int* __restrict__ batch,
    const unsigned short* __restrict__ Wg,
    const float* __restrict__ b1, const float* __restrict__ w2,
    const float* __restrict__ b2,
    float* __restrict__ out, float* __restrict__ den)
{
  __shared__ char  XS[8 * 16384];   // 128KB: 2 tiles x 4 K-slices (128r x 32k fp32)
  __shared__ float p4[4][128];      // per-ch-group partial w2-dots
  __shared__ float es[128];         // exp(score) per row
  __shared__ int   bsL[2][128];     // graph id per row, double-buffered

  const int tid = threadIdx.x;
  const int w   = tid >> 6;     // wave 0..7
  const int l   = tid & 63;
  const int l15 = l & 15;
  const int g   = l >> 4;       // 0..3
  const int rw  = w & 1;        // row half: rows rw*64 .. +63 (4 nt)
  const int cw  = w >> 1;       // ch quarter: ch cw*32 .. +31 (2 ct)

  const int bid = blockIdx.x;
  const int ntb = (TILES - 1 - bid) / GRID + 1;
  const bool is64 = (batch[NN - 1] == 0);   // int64-vs-int32 runtime hedge
  const float b2v = b2[0];

  float b1r[2], w2r[2];
  #pragma unroll
  for (int ctk = 0; ctk < 2; ++ctk){
    const int n = (cw * 2 + ctk) * 16 + l15;
    b1r[ctk] = b1[n];
    w2r[ctk] = w2[n];
  }

  // W fragments -> registers (64 VGPR), constant across tiles.
  short8v Bf[2][4][2];
  #pragma unroll
  for (int ctk = 0; ctk < 2; ++ctk){
    const int n = (cw * 2 + ctk) * 16 + l15;
    #pragma unroll
    for (int kc = 0; kc < 4; ++kc){
      Bf[ctk][kc][0] = *reinterpret_cast<const short8v*>(Wg + n * 128 + kc * 32 + g * 8);
      Bf[ctk][kc][1] = *reinterpret_cast<const short8v*>(Wg + 16384 + n * 128 + kc * 32 + g * 8);
    }
  }

  // Stage K-slice ks of tile (loop-index i1, global t1) into half (i1&1).
  // LDS[R][c] = src[R][c ^ (R&7)]  (linear dest, pre-swizzled source).
  auto stage_slice = [&](int i1, int t1, int ks){
    char* base = XS + ((i1 & 1) * 4 + ks) * 16384;
    #pragma unroll
    for (int p = 0; p < 2; ++p){
      const int idx = p * 512 + tid;   // 16B chunk 0..1023
      const int R = idx >> 3, c = idx & 7;
      int row = t1 * 128 + R;
      row = row < NN ? row : NN - 1;   // clamp; es=0 masks contribution
      const char* gsrc = (const char*)x + (size_t)row * 512 + ks * 128 + ((c ^ (R & 7)) << 4);
      gld_lds16(gsrc, base + idx * 16);
    }
  };
  // Stage batch ids for tile (i1,t1) (waves 0-1 only; +1 vmem op for them).
  auto stage_bsg = [&](int i1, int t1){
    if (w < 2){
      int row = t1 * 128 + w * 64 + l;
      row = row < NN ? row : NN - 1;
      const char* gsrc = (const char*)batch + (size_t)(is64 ? 2 * row : row) * 4;
      gld_lds4(gsrc, (char*)&bsL[i1 & 1][w * 64 + l]);
    }
  };

  stage_slice(0, bid, 0); stage_slice(0, bid, 1);
  stage_slice(0, bid, 2); stage_slice(0, bid, 3);
  stage_bsg(0, bid);
  __syncthreads();   // one-time full drain

  for (int i = 0; i < ntb; ++i){
    const int tglob = bid + i * GRID;
    const bool hasnext = (i + 1) < ntb;
    const int tgn = tglob + GRID;

    f32x4 acc[4][2];
    #pragma unroll
    for (int a = 0; a < 4; ++a)
      #pragma unroll
      for (int b = 0; b < 2; ++b) acc[a][b] = (f32x4)0.f;

    #pragma unroll
    for (int ks = 0; ks < 4; ++ks){
      asm volatile("s_waitcnt vmcnt(6)" ::: "memory");
      __builtin_amdgcn_s_barrier();
      if (hasnext){
        stage_slice(i + 1, tgn, ks);
        if (ks == 3) stage_bsg(i + 1, tgn);
      }
      const char* sb = XS + ((i & 1) * 4 + ks) * 16384;

      // A fragments: lane l -> x[R = rw*64+nt*16+l15][k = ks*32 + g*8 + j]
      short8v Ah[4], Al[4];
      #pragma unroll
      for (int nt = 0; nt < 4; ++nt){
        const int R = rw * 64 + nt * 16 + l15;
        const char* bp = sb + R * 128;
        float fv[8];
        *reinterpret_cast<float4*>(fv) =
            *reinterpret_cast<const float4*>(bp + (((2 * g)     ^ (R & 7)) << 4));
        *reinterpret_cast<float4*>(fv + 4) =
            *reinterpret_cast<const float4*>(bp + (((2 * g + 1) ^ (R & 7)) << 4));
        unsigned short hv[8], lv[8];
        #pragma unroll
        for (int j = 0; j < 8; j++) bf16_split(fv[j], hv[j], lv[j]);
        Ah[nt] = *reinterpret_cast<short8v*>(hv);
        Al[nt] = *reinterpret_cast<short8v*>(lv);
      }
      #pragma unroll
      for (int nt = 0; nt < 4; ++nt){
        #pragma unroll
        for (int ctk = 0; ctk < 2; ++ctk){
          acc[nt][ctk] = __builtin_amdgcn_mfma_f32_16x16x32_bf16(Ah[nt], Bf[ctk][ks][0], acc[nt][ctk], 0, 0, 0);
          acc[nt][ctk] = __builtin_amdgcn_mfma_f32_16x16x32_bf16(Al[nt], Bf[ctk][ks][0], acc[nt][ctk], 0, 0, 0);
          acc[nt][ctk] = __builtin_amdgcn_mfma_f32_16x16x32_bf16(Ah[nt], Bf[ctk][ks][1], acc[nt][ctk], 0, 0, 0);
        }
      }
    }

    // ---- partial score dots: p4[cw][row] (D-layout: row16 = g*4 + r) ----
    #pragma unroll
    for (int nt = 0; nt < 4; ++nt){
      #pragma unroll
      for (int r = 0; r < 4; ++r){
        float s = fmaxf(acc[nt][0][r] + b1r[0], 0.f) * w2r[0];
        s = fmaf(fmaxf(acc[nt][1][r] + b1r[1], 0.f), w2r[1], s);
        s += __shfl_xor(s, 1); s += __shfl_xor(s, 2);
        s += __shfl_xor(s, 4); s += __shfl_xor(s, 8);
        if (l15 == 0) p4[cw][rw * 64 + nt * 16 + g * 4 + r] = s;
      }
    }
    asm volatile("s_waitcnt lgkmcnt(0)" ::: "memory");
    __builtin_amdgcn_s_barrier();

    if (tid < 128){
      const float s = p4[0][tid] + p4[1][tid] + p4[2][tid] + p4[3][tid] + b2v;
      es[tid] = (tglob * 128 + tid < NN) ? __expf(s) : 0.f;
    }
    asm volatile("s_waitcnt lgkmcnt(0)" ::: "memory");
    __builtin_amdgcn_s_barrier();

    // ---- pooling from LDS: c4 = float4 column, 8 contiguous rows/thread ----
    {
      const int half = i & 1;
      const int c4 = tid & 31;
      const int rgg = tid >> 5;          // 0..15
      const char* sbase = XS + (half * 4 + (c4 >> 3)) * 16384;
      const int ch = c4 & 7;             // chunk within slice
      float4 ap = make_float4(0.f, 0.f, 0.f, 0.f);
      float dp = 0.f;
      int gprev = bsL[half][rgg * 8];
      #pragma unroll
      for (int rr = 0; rr < 8; ++rr){
        const int r = rgg * 8 + rr;
        const int gg = bsL[half][r];
        if (gg != gprev){
          atomicAdd(&out[(size_t)gprev * CH + c4 * 4 + 0], ap.x);
          atomicAdd(&out[(size_t)gprev * CH + c4 * 4 + 1], ap.y);
          atomicAdd(&out[(size_t)gprev * CH + c4 * 4 + 2], ap.z);
          atomicAdd(&out[(size_t)gprev * CH + c4 * 4 + 3], ap.w);
          if (c4 == 0) atomicAdd(&den[gprev], dp);
          ap = make_float4(0.f, 0.f, 0.f, 0.f); dp = 0.f; gprev = gg;
        }
        const float e = es[r];
        const float4 v = *reinterpret_cast<const float4*>(
            sbase + r * 128 + ((ch ^ (r & 7)) << 4));
        ap.x = fmaf(e, v.x, ap.x); ap.y = fmaf(e, v.y, ap.y);
        ap.z = fmaf(e, v.z, ap.z); ap.w = fmaf(e, v.w, ap.w);
        if (c4 == 0) dp += e;
      }
      atomicAdd(&out[(size_t)gprev * CH + c4 * 4 + 0], ap.x);
      atomicAdd(&out[(size_t)gprev * CH + c4 * 4 + 1], ap.y);
      atomicAdd(&out[(size_t)gprev * CH + c4 * 4 + 2], ap.z);
      atomicAdd(&out[(size_t)gprev * CH + c4 * 4 + 3], ap.w);
      if (c4 == 0) atomicAdd(&den[gprev], dp);
    }
    // next iteration's phase-0 barrier orders pooling reads vs restaging
  }
}

// Normalize: out[g][c] /= den[g] (0 for empty graphs)
__global__ __launch_bounds__(256) void norm_kernel(
    float* __restrict__ out, const float* __restrict__ den){
  const int idx = blockIdx.x * 256 + threadIdx.x;   // float4 index
  if (idx >= NG * 32) return;
  const int gidx = idx >> 5;
  const float d = den[gidx];
  const float inv = d > 0.f ? 1.f / d : 0.f;
  float4 v = reinterpret_cast<float4*>(out)[idx];
  v.x *= inv; v.y *= inv; v.z *= inv; v.w *= inv;
  reinterpret_cast<float4*>(out)[idx] = v;
}

extern "C" void kernel_launch(void* const* d_in, const int* in_sizes, int n_in,
                              void* d_out, int out_size, void* d_ws, size_t ws_size,
                              hipStream_t stream){
  const float* x    = (const float*)d_in[0];
  const int*   batch= (const int*)d_in[1];
  const float* W1   = (const float*)d_in[2];
  const float* b1   = (const float*)d_in[3];
  const float* w2   = (const float*)d_in[4];
  const float* b2   = (const float*)d_in[5];
  float* out = (float*)d_out;

  unsigned short* Wg = (unsigned short*)d_ws;     // 64KB pre-split W (linear)
  float* den = (float*)((char*)d_ws + 65536);     // NG floats

  prep_kernel<<<40, 256, 0, stream>>>(W1, Wg, out, den);
  fused_kernel<<<GRID, 512, 0, stream>>>(x, batch, Wg, b1, w2, b2, out, den);
  norm_kernel<<<128, 256, 0, stream>>>(out, den);
}

// Round 10
// 135.819 us; speedup vs baseline: 2.2507x; 2.2507x over previous
//
#include <hip/hip_runtime.h>
#include <math.h>

#define NN 500000
#define CH 128
#define NG 1024
#define GRID_S 512
#define TILES ((NN + 127) >> 7)   // 3907 tiles of 128 rows

typedef __attribute__((ext_vector_type(8))) short short8v;
typedef __attribute__((ext_vector_type(4))) float f32x4;

__device__ __forceinline__ void bf16_split(float f, unsigned short& h, unsigned short& l){
  const unsigned u = __float_as_uint(f);
  h = (unsigned short)(u >> 16);
  const float hif = __uint_as_float(u & 0xffff0000u);
  const float lof = f - hif;
  l = (unsigned short)(__float_as_uint(lof) >> 16);
}

__device__ __forceinline__ void gld_lds16(const void* g, void* l){
  __builtin_amdgcn_global_load_lds(
      (__attribute__((address_space(1))) void*)g,
      (__attribute__((address_space(3))) void*)l, 16, 0, 0);
}

// Convert 8 fp32 (two float4) -> bf16 hi fragment + lo fragment.
__device__ __forceinline__ void cvt8(const float4 f0, const float4 f1,
                                     short8v& Ah, short8v& Al){
  float fv[8];
  *reinterpret_cast<float4*>(fv) = f0;
  *reinterpret_cast<float4*>(fv + 4) = f1;
  unsigned short hv[8], lv[8];
  #pragma unroll
  for (int j = 0; j < 8; j++) bf16_split(fv[j], hv[j], lv[j]);
  Ah = *reinterpret_cast<short8v*>(hv);
  Al = *reinterpret_cast<short8v*>(lv);
}

// Prep: (a) t<2048: transpose + bf16-hi/lo-split W1 into Wg, LINEAR layout:
// hi[n][k] at Wg + n*128 + k, lo at Wg + 16384 + n*128 + k (ushort units).
// (b) t in [2048, 2048+NG]: segment boundaries via lower_bound on sorted batch.
__global__ __launch_bounds__(256) void prep_kernel(
    const float* __restrict__ W1, unsigned short* __restrict__ Wg,
    const int* __restrict__ batch, int* __restrict__ start){
  const int t = blockIdx.x * 256 + threadIdx.x;
  if (t < 2048){
    const int n  = t >> 4;
    const int k0 = (t & 15) << 3;
    unsigned short hv[8], lv[8];
    #pragma unroll
    for (int i = 0; i < 8; i++)
      bf16_split(W1[(size_t)(k0 + i) * CH + n], hv[i], lv[i]);
    *reinterpret_cast<short8v*>(Wg + n * 128 + k0) = *reinterpret_cast<short8v*>(hv);
    *reinterpret_cast<short8v*>(Wg + 16384 + n * 128 + k0) = *reinterpret_cast<short8v*>(lv);
  } else if (t <= 2048 + NG){
    const int g = t - 2048;
    const bool is64 = (batch[NN - 1] == 0);   // int64-vs-int32 runtime hedge
    if (g == NG){ start[NG] = NN; return; }
    int lo = 0, hi = NN;
    while (lo < hi){
      int mid = (lo + hi) >> 1;
      int v = is64 ? batch[2 * mid] : batch[mid];
      if (v < g) lo = mid + 1; else hi = mid;
    }
    start[g] = lo;
  }
}

// K1: escore[n] = exp(relu(x[n]@W1 + b1).w2 + b2).
// 512 thr (8 waves: 2 row-halves x 4 ch-quarters), W ENTIRELY IN REGISTERS
// (no B LDS reads), 4 x 16KB K-slice slots, depth-2 counted-vmcnt pipeline.
// Per-wave exact vmcnt bookkeeping (in-order retirement):
//   steady: queue at phase entry = [slice P (2), slice P+1 (2)] -> vmcnt(2).
//   waves 0-1 after a tile store, ks<=1: [sliceP(2), sliceP+1(2), store] or
//   [sliceP(2), store, sliceP+1(2)] -> vmcnt(3). Final phase: vmcnt(0).
__global__ __launch_bounds__(512, 4) void scores_mfma(
    const float* __restrict__ x, const unsigned short* __restrict__ Wg,
    const float* __restrict__ b1, const float* __restrict__ w2,
    const float* __restrict__ b2, float* __restrict__ escore)
{
  __shared__ char  XS[4 * 16384];   // 4 slots: 128 rows x 32 k fp32 (swizzled)
  __shared__ float p4[4][128];      // per-ch-quarter partial w2-dots
  __shared__ float b1s[CH], w2s[CH];

  const int tid = threadIdx.x;
  const int w   = tid >> 6;     // wave 0..7
  const int l   = tid & 63;
  const int l15 = l & 15;
  const int g   = l >> 4;       // 0..3
  const int rw  = w & 1;        // row half (64 rows)
  const int cw  = w >> 1;       // ch quarter (32 ch)

  const int bid = blockIdx.x;
  const int ntb = (TILES - 1 - bid) / GRID_S + 1;
  const int NP  = ntb * 4;
  const float b2v = b2[0];

  if (tid < CH){ b1s[tid] = b1[tid]; w2s[tid] = w2[tid]; }

  // W fragments -> registers (64 VGPR), constant across tiles.
  short8v Bf[2][4][2];
  #pragma unroll
  for (int ctk = 0; ctk < 2; ++ctk){
    const int n = (cw * 2 + ctk) * 16 + l15;
    #pragma unroll
    for (int kc = 0; kc < 4; ++kc){
      Bf[ctk][kc][0] = *reinterpret_cast<const short8v*>(Wg + n * 128 + kc * 32 + g * 8);
      Bf[ctk][kc][1] = *reinterpret_cast<const short8v*>(Wg + 16384 + n * 128 + kc * 32 + g * 8);
    }
  }

  // Per-thread staging constants: thread handles chunks p*512+tid, p=0,1.
  // chunk idx -> (R = idx>>3, c = idx&7); LDS[R][c] = src[R][c ^ (R&7)].
  int srcoff[2], dstoff[2];
  #pragma unroll
  for (int p = 0; p < 2; ++p){
    const int idx = p * 512 + tid;
    const int R = idx >> 3, c = idx & 7;
    srcoff[p] = R * 512 + ((c ^ (R & 7)) << 4);   // bytes within tile's k-slice pane
    dstoff[p] = idx * 16;
  }
  // Stage slice SL (tile SL>>2, k-slice SL&3) into slot SL&3. 2 ops/thread.
  auto stage = [&](int SL){
    char* base = XS + (SL & 3) * 16384;
    const size_t tb = (size_t)(bid + (SL >> 2) * GRID_S) * 65536 + (SL & 3) * 128;
    #pragma unroll
    for (int p = 0; p < 2; ++p){
      size_t so = tb + srcoff[p];
      if (so >= (size_t)NN * 512) so = (size_t)(NN - 1) * 512;  // clamp (guarded store)
      gld_lds16((const char*)x + so, base + dstoff[p]);
    }
  };

  // A-read addressing: R = rw*64 + nt*16 + l15 -> R&7 = l15&7 (nt-indep).
  const int abase = (rw * 64 + l15) * 128;
  const int sw0 = ((2 * g)     ^ (l15 & 7)) << 4;
  const int sw1 = ((2 * g + 1) ^ (l15 & 7)) << 4;

  stage(0); stage(1);
  asm volatile("s_waitcnt vmcnt(0) lgkmcnt(0)" ::: "memory");
  __syncthreads();   // one-time full drain: Bf/b1s/w2s/slots 0,1 ready

  for (int ti = 0; ti < ntb; ++ti){
    const int tilebase = (bid + ti * GRID_S) * 128;

    f32x4 acc[4][2];
    #pragma unroll
    for (int a = 0; a < 4; ++a)
      #pragma unroll
      for (int b = 0; b < 2; ++b) acc[a][b] = (f32x4)0.f;

    #pragma unroll
    for (int ks = 0; ks < 4; ++ks){
      const int P = ti * 4 + ks;
      // exact counted wait (see header comment)
      if (ti == ntb - 1 && ks == 3)
        asm volatile("s_waitcnt vmcnt(0)" ::: "memory");
      else if (ks <= 1 && w < 2 && ti > 0)
        asm volatile("s_waitcnt vmcnt(3)" ::: "memory");
      else
        asm volatile("s_waitcnt vmcnt(2)" ::: "memory");
      __builtin_amdgcn_s_barrier();
      if (P + 2 < NP) stage(P + 2);

      const char* sb = XS + ks * 16384;
      #pragma unroll
      for (int nt = 0; nt < 4; ++nt){
        const char* bp = sb + abase + nt * 2048;
        short8v Ah, Al;
        cvt8(*reinterpret_cast<const float4*>(bp + sw0),
             *reinterpret_cast<const float4*>(bp + sw1), Ah, Al);
        #pragma unroll
        for (int ctk = 0; ctk < 2; ++ctk){
          acc[nt][ctk] = __builtin_amdgcn_mfma_f32_16x16x32_bf16(Ah, Bf[ctk][ks][0], acc[nt][ctk], 0, 0, 0);
          acc[nt][ctk] = __builtin_amdgcn_mfma_f32_16x16x32_bf16(Al, Bf[ctk][ks][0], acc[nt][ctk], 0, 0, 0);
          acc[nt][ctk] = __builtin_amdgcn_mfma_f32_16x16x32_bf16(Ah, Bf[ctk][ks][1], acc[nt][ctk], 0, 0, 0);
        }
      }
    }

    // Epilogue: partial dots -> p4[cw][row]; 128 threads finish + store exp.
    const float b1v0 = b1s[cw * 32 + l15], b1v1 = b1s[cw * 32 + 16 + l15];
    const float w2v0 = w2s[cw * 32 + l15], w2v1 = w2s[cw * 32 + 16 + l15];
    #pragma unroll
    for (int nt = 0; nt < 4; ++nt){
      #pragma unroll
      for (int r = 0; r < 4; ++r){
        float s = fmaxf(acc[nt][0][r] + b1v0, 0.f) * w2v0;
        s = fmaf(fmaxf(acc[nt][1][r] + b1v1, 0.f), w2v1, s);
        s += __shfl_xor(s, 1); s += __shfl_xor(s, 2);
        s += __shfl_xor(s, 4); s += __shfl_xor(s, 8);
        if (l15 == 0) p4[cw][rw * 64 + nt * 16 + g * 4 + r] = s;
      }
    }
    asm volatile("s_waitcnt lgkmcnt(0)" ::: "memory");
    __builtin_amdgcn_s_barrier();
    if (tid < 128){
      const float s = p4[0][tid] + p4[1][tid] + p4[2][tid] + p4[3][tid] + b2v;
      const int grow = tilebase + tid;
      if (grow < NN) escore[grow] = __expf(s);
    }
    // next tile's phase-0 barrier separates p4 reuse
  }
}

// Pool: out[g][c] = sum_i es[i]*x[i][c] / sum_i es[i]. Single pass,
// two independent acc chains for memory-level parallelism.
__global__ __launch_bounds__(256) void pool_kernel(
    const float* __restrict__ x, const float* __restrict__ es,
    const int* __restrict__ start, float* __restrict__ out){
  const int g = blockIdx.x;
  const int s0 = start[g], s1 = start[g + 1];
  const int tid = threadIdx.x;
  const int c4 = tid & 31;   // float4 column
  const int rg = tid >> 5;   // row group 0..7

  float4 a0 = make_float4(0.f, 0.f, 0.f, 0.f);
  float4 a1 = make_float4(0.f, 0.f, 0.f, 0.f);
  float d0 = 0.f, d1 = 0.f;
  int i = s0 + rg;
  for (; i + 8 < s1; i += 16){
    const float e0 = es[i];
    const float e1 = es[i + 8];
    const float4 v0 = reinterpret_cast<const float4*>(&x[(size_t)i * CH])[c4];
    const float4 v1 = reinterpret_cast<const float4*>(&x[(size_t)(i + 8) * CH])[c4];
    a0.x = fmaf(e0, v0.x, a0.x); a0.y = fmaf(e0, v0.y, a0.y);
    a0.z = fmaf(e0, v0.z, a0.z); a0.w = fmaf(e0, v0.w, a0.w);
    d0 += e0;
    a1.x = fmaf(e1, v1.x, a1.x); a1.y = fmaf(e1, v1.y, a1.y);
    a1.z = fmaf(e1, v1.z, a1.z); a1.w = fmaf(e1, v1.w, a1.w);
    d1 += e1;
  }
  if (i < s1){
    const float e0 = es[i];
    const float4 v0 = reinterpret_cast<const float4*>(&x[(size_t)i * CH])[c4];
    a0.x = fmaf(e0, v0.x, a0.x); a0.y = fmaf(e0, v0.y, a0.y);
    a0.z = fmaf(e0, v0.z, a0.z); a0.w = fmaf(e0, v0.w, a0.w);
    d0 += e0;
  }
  a0.x += a1.x; a0.y += a1.y; a0.z += a1.z; a0.w += a1.w;
  d0 += d1;

  __shared__ float4 red[8][32];
  __shared__ float redd[8][32];
  red[rg][c4] = a0;
  redd[rg][c4] = d0;
  __syncthreads();
  if (rg < 4){
    float4 o = red[rg + 4][c4], m = red[rg][c4];
    m.x += o.x; m.y += o.y; m.z += o.z; m.w += o.w;
    red[rg][c4] = m;
    redd[rg][c4] += redd[rg + 4][c4];
  }
  __syncthreads();
  if (rg < 2){
    float4 o = red[rg + 2][c4], m = red[rg][c4];
    m.x += o.x; m.y += o.y; m.z += o.z; m.w += o.w;
    red[rg][c4] = m;
    redd[rg][c4] += redd[rg + 2][c4];
  }
  __syncthreads();
  if (rg == 0){
    float4 b0 = red[0][c4], b1v = red[1][c4];
    const float d = redd[0][c4] + redd[1][c4];
    const float inv = d > 0.f ? 1.f / d : 0.f;
    float4 r;
    r.x = (b0.x + b1v.x) * inv; r.y = (b0.y + b1v.y) * inv;
    r.z = (b0.z + b1v.z) * inv; r.w = (b0.w + b1v.w) * inv;
    reinterpret_cast<float4*>(&out[(size_t)g * CH])[c4] = r;
  }
}

extern "C" void kernel_launch(void* const* d_in, const int* in_sizes, int n_in,
                              void* d_out, int out_size, void* d_ws, size_t ws_size,
                              hipStream_t stream){
  const float* x    = (const float*)d_in[0];
  const int*   batch= (const int*)d_in[1];
  const float* W1   = (const float*)d_in[2];
  const float* b1   = (const float*)d_in[3];
  const float* w2   = (const float*)d_in[4];
  const float* b2   = (const float*)d_in[5];
  float* out = (float*)d_out;

  float* es    = (float*)d_ws;                                      // NN floats
  int*   start = (int*)((char*)d_ws + (size_t)NN * sizeof(float));  // NG+1 ints
  unsigned short* Wg = (unsigned short*)((char*)d_ws + ((ws_size - 65536) & ~(size_t)255));

  prep_kernel<<<13, 256, 0, stream>>>(W1, Wg, batch, start);
  scores_mfma<<<GRID_S, 512, 0, stream>>>(x, Wg, b1, w2, b2, es);
  pool_kernel<<<NG, 256, 0, stream>>>(x, es, start, out);
}